// Round 8
// baseline (40.706 us; speedup 1.0000x reference)
//
#include <hip/hip_runtime.h>
#include <hip/hip_bf16.h>
#include <cstdint>

#define NROWS 262144
#define DIM 128

typedef float f32x4 __attribute__((ext_vector_type(4)));
typedef short s16x8 __attribute__((ext_vector_type(8)));
typedef unsigned short u16x8 __attribute__((ext_vector_type(8)));
typedef unsigned int u32x4 __attribute__((ext_vector_type(4)));

__device__ __forceinline__ unsigned short cvbf(float f){
  unsigned u = __float_as_uint(f);
  return (unsigned short)((u + 0x8000u) >> 16);
}

__device__ __forceinline__ void ldsload16(const void* gp, void* lp){
  __builtin_amdgcn_global_load_lds((const __attribute__((address_space(1))) void*)gp,
                                   (__attribute__((address_space(3))) void*)lp,
                                   16, 0, 0);
}

// ---------------- prep kernel: weight repack + dtype detect into d_ws ----------------
// ws[0..65536): W1T bf16, row n=g*64+h (256 x 256B), byte = n*256 + (k*2 ^ ((n&7)<<4))
// ws[65536..73728): W2T bf16, row t=g*16+p (64 x 128B); element slot e (=ks*32+q*8+j)
//   holds W2[g][h(e)][p], h(e) = (e&32)|((e&4)<<2)|((e>>1)&12)|(e&3)  (k-slot permutation
//   matching GEMM1's C^T fragment layout -> GEMM2 needs no hidden transpose), p>=4 zeros.
// ws[73728]: gshift (0=int32 gids, 1=int64) ; ws[73732]: mshift (0=byte mask, 2=int32 mask)
__global__ void prep_kernel(const float* __restrict__ W1, const float* __restrict__ W2,
                            const void* __restrict__ gids_raw, const void* __restrict__ mask_raw,
                            unsigned char* __restrict__ ws){
  int tid = threadIdx.x, bid = blockIdx.x;
  if (bid < 16){
    int chunk = bid*256 + tid;
    int n    = chunk >> 4;
    int kb16 = chunk & 15;
    int d0   = kb16 * 8;
    int g = n >> 6, h = n & 63;
    u16x8 v;
#pragma unroll
    for (int j=0;j<8;++j) v[j] = cvbf(W1[((g*DIM) + d0 + j)*64 + h]);
    unsigned off = (unsigned)n*256 + (((unsigned)kb16*16) ^ (((unsigned)(n&7))<<4));
    *(u16x8*)(ws + off) = v;
  } else {
#pragma unroll
    for (int i=0;i<16;++i){
      int el = tid + i*256;          // 0..4095 elements of W2T
      int t  = el >> 6;              // row t = g*16+p
      int e  = el & 63;              // k-slot within row
      int g = t >> 4, p = t & 15;
      int h = (e & 32) | ((e & 4) << 2) | ((e >> 1) & 12) | (e & 3);
      float f = (p < 4) ? W2[(g*64 + h)*4 + p] : 0.0f;
      unsigned off = 65536u + (unsigned)t*128 + (((unsigned)(e*2)) ^ (((unsigned)(t&7))<<4));
      *(unsigned short*)(ws + off) = cvbf(f);
    }
    if (tid < 64){
      const int* g32 = (const int*)gids_raw;
      int accg = 0;
#pragma unroll
      for (int i=0;i<8;++i) accg |= g32[(tid*8 + i)*2 + 1];
      const unsigned char* m8 = (const unsigned char*)mask_raw;
      int accm = 0;
#pragma unroll
      for (int i=0;i<16;++i){
        int off = tid*16 + i;
        if (off & 3) accm |= m8[off];
      }
      unsigned long long bg = __ballot(accg != 0);
      unsigned long long bm = __ballot(accm != 0);
      if (tid == 0){
        *(int*)(ws + 73728) = (bg == 0ull) ? 1 : 0;
        *(int*)(ws + 73732) = (bm == 0ull) ? 2 : 0;
      }
    }
  }
}

// ---------------- main kernel: persistent, pinned schedule, double-buffered X prefetch ----------------
#define LDS_W2T 65536
#define LDS_B1  (65536+8192)
#define LDS_TOTAL (65536+8192+1024)

// One 16-row unit: uses CUR X regs, prefetches NXT (unit UIDX+1) if DO_PF.
#define HALF_STEP(CUR, NXT, UIDX, DO_PF)                                          \
  {                                                                               \
    const long row_ = base + (UIDX)*16 + rS;                                      \
    int gb = gids[(size_t)row_ << gshift];                                        \
    u32x4 mb;                                                                     \
    if (mshift){ mb = *(const u32x4*)(fmask + row_*16); }                         \
    else { unsigned w_ = *(const unsigned*)(fmask + row_*4);                      \
           mb[0]=w_&0xffu; mb[1]=(w_>>8)&0xffu; mb[2]=(w_>>16)&0xffu; mb[3]=w_>>24; } \
    if (DO_PF){                                                                   \
      const float* xp_ = X + (row_ + 16) * DIM + q*8;                             \
      _Pragma("unroll")                                                           \
      for (int k=0;k<4;++k){                                                      \
        NXT[k][0] = *(const f32x4*)(xp_ + k*32);                                  \
        NXT[k][1] = *(const f32x4*)(xp_ + k*32 + 4);                              \
      }                                                                           \
    }                                                                             \
    __builtin_amdgcn_sched_barrier(0);                                            \
    s16x8 bfr[4];                                                                 \
    _Pragma("unroll")                                                             \
    for (int k=0;k<4;++k){                                                        \
      s16x8 v_;                                                                   \
      _Pragma("unroll")                                                           \
      for (int j=0;j<4;++j){ v_[j] = (short)cvbf(CUR[k][0][j]);                   \
                             v_[j+4] = (short)cvbf(CUR[k][1][j]); }               \
      bfr[k] = v_;                                                                \
    }                                                                             \
    __builtin_amdgcn_sched_barrier(0);                                            \
    f32x4 acc2[4];                                                                \
    _Pragma("unroll")                                                             \
    for (int p=0;p<8;++p){                                                        \
      f32x4 aA, aB;                                                               \
      _Pragma("unroll")                                                           \
      for (int k=0;k<4;++k){                                                      \
        const s16x8 sA = *(const s16x8*)(smem + ((2*p  )*16 + rS)*256 + ((k*64 + q*16) ^ swzA)); \
        const s16x8 sB = *(const s16x8*)(smem + ((2*p+1)*16 + rS)*256 + ((k*64 + q*16) ^ swzA)); \
        aA = __builtin_amdgcn_mfma_f32_16x16x32_bf16(sA, bfr[k], (k==0)? z : aA, 0,0,0); \
        aB = __builtin_amdgcn_mfma_f32_16x16x32_bf16(sB, bfr[k], (k==0)? z : aB, 0,0,0); \
      }                                                                           \
      const f32x4 b1A = *(const f32x4*)(smem + LDS_B1 + (2*p  )*64 + q*16);       \
      const f32x4 b1B = *(const f32x4*)(smem + LDS_B1 + (2*p+1)*64 + q*16);       \
      f32x4 vA = aA + b1A;                                                        \
      f32x4 vB = aB + b1B;                                                        \
      _Pragma("unroll")                                                           \
      for (int j=0;j<4;++j){                                                      \
        vA[j] = vA[j] > 0.f ? vA[j] : 0.f;                                        \
        vB[j] = vB[j] > 0.f ? vB[j] : 0.f;                                        \
      }                                                                           \
      s16x8 hf;                                                                   \
      _Pragma("unroll")                                                           \
      for (int j=0;j<4;++j){                                                      \
        hf[j]   = (short)cvbf(vA[j]);                                             \
        hf[j+4] = (short)cvbf(vB[j]);                                             \
      }                                                                           \
      const s16x8 af = *(const s16x8*)(smem + LDS_W2T + ((p>>1)*16 + rS)*128      \
                                       + (((p&1)*64 + q*16) ^ swzA));             \
      acc2[p>>1] = __builtin_amdgcn_mfma_f32_16x16x32_bf16(                       \
          af, hf, (p&1) ? acc2[p>>1] : z, 0,0,0);                                 \
      __builtin_amdgcn_sched_barrier(0);                                          \
    }                                                                             \
    {                                                                             \
      int g_ = gb;                                                                \
      f32x4 lv = acc2[0];                                                         \
      lv = (g_==1) ? acc2[1] : lv;                                                \
      lv = (g_==2) ? acc2[2] : lv;                                                \
      lv = (g_==3) ? acc2[3] : lv;                                                \
      const f32x4 bs = *(const f32x4*)(b2 + g_*4);                                \
      f32x4 li;                                                                   \
      _Pragma("unroll")                                                           \
      for (int p=0;p<4;++p)                                                       \
        li[p] = mb[p] ? (lv[p] + bs[p]) : -1e9f;                                  \
      float m_ = fmaxf(fmaxf(li[0],li[1]), fmaxf(li[2],li[3]));                   \
      f32x4 e_;                                                                   \
      _Pragma("unroll")                                                           \
      for (int p=0;p<4;++p) e_[p] = __expf(li[p] - m_);                           \
      float inv_ = 1.0f / (e_[0]+e_[1]+e_[2]+e_[3]);                              \
      f32x4 o_;                                                                   \
      _Pragma("unroll")                                                           \
      for (int p=0;p<4;++p) o_[p] = e_[p] * inv_;                                 \
      if (q == 0)                                                                 \
        *(f32x4*)(out + row_*4) = o_;                                             \
    }                                                                             \
  }

__global__ __launch_bounds__(256, 2)
void actor_kernel(const float* __restrict__ X, const int* __restrict__ gids,
                  const unsigned char* __restrict__ fmask,
                  const float* __restrict__ b1, const float* __restrict__ b2,
                  const unsigned char* __restrict__ ws, float* __restrict__ out){
  __shared__ char smem[LDS_TOTAL];
  const int tid  = threadIdx.x;
  const int wave = tid >> 6, lane = tid & 63;
  const int q    = lane >> 4, rS = lane & 15;
  const int swzA = (rS & 7) << 4;

  const int gshift = *(const int*)(ws + 73728);
  const int mshift = *(const int*)(ws + 73732);

  // --- stage W1T + W2T + b1 to LDS once per block ---
#pragma unroll
  for (int i=0;i<16;++i){
    int off = i*4096 + wave*1024;
    ldsload16(ws + off + lane*16, smem + off);
  }
#pragma unroll
  for (int i=0;i<2;++i){
    int off = i*4096 + wave*1024;
    ldsload16(ws + 65536 + off + lane*16, smem + LDS_W2T + off);
  }
  if (wave == 0)
    ldsload16((const unsigned char*)b1 + lane*16, smem + LDS_B1);

  const long base = (long)blockIdx.x * 512 + wave * 128;
  const f32x4 z = (f32x4){0.f,0.f,0.f,0.f};

  f32x4 xbA[4][2], xbB[4][2];
  // prologue: load unit 0 into xbA
  {
    const float* xp = X + (base + rS) * DIM + q*8;
#pragma unroll
    for (int k=0;k<4;++k){
      xbA[k][0] = *(const f32x4*)(xp + k*32);
      xbA[k][1] = *(const f32x4*)(xp + k*32 + 4);
    }
  }
  __syncthreads();   // weights resident

#pragma unroll 1
  for (int uu=0; uu<4; ++uu){
    HALF_STEP(xbA, xbB, uu*2,     1)
    HALF_STEP(xbB, xbA, uu*2 + 1, (uu < 3))
  }
}

extern "C" void kernel_launch(void* const* d_in, const int* in_sizes, int n_in,
                              void* d_out, int out_size, void* d_ws, size_t ws_size,
                              hipStream_t stream){
  const float* X  = (const float*)d_in[0];
  const void*  gi = d_in[1];
  const void*  fm = d_in[2];
  const float* W1 = (const float*)d_in[3];
  const float* b1 = (const float*)d_in[4];
  const float* W2 = (const float*)d_in[5];
  const float* b2 = (const float*)d_in[6];
  unsigned char* ws = (unsigned char*)d_ws;
  float* out = (float*)d_out;

  prep_kernel<<<dim3(17), dim3(256), 0, stream>>>(W1, W2, gi, fm, ws);
  actor_kernel<<<dim3(512), dim3(256), 0, stream>>>(X, (const int*)gi,
                                                    (const unsigned char*)fm,
                                                    b1, b2, ws, out);
}

// Round 9
// 37.719 us; speedup vs baseline: 1.0792x; 1.0792x over previous
//
#include <hip/hip_runtime.h>
#include <hip/hip_bf16.h>
#include <cstdint>

#define NROWS 262144
#define DIM 128

typedef float f32x4 __attribute__((ext_vector_type(4)));
typedef short s16x8 __attribute__((ext_vector_type(8)));
typedef unsigned short u16x8 __attribute__((ext_vector_type(8)));
typedef unsigned int u32x4 __attribute__((ext_vector_type(4)));

__device__ __forceinline__ unsigned short cvbf(float f){
  unsigned u = __float_as_uint(f);
  return (unsigned short)((u + 0x8000u) >> 16);
}

__device__ __forceinline__ void ldsload16(const void* gp, void* lp){
  __builtin_amdgcn_global_load_lds((const __attribute__((address_space(1))) void*)gp,
                                   (__attribute__((address_space(3))) void*)lp,
                                   16, 0, 0);
}

// ---------------- prep kernel: weight repack + dtype detect into d_ws ----------------
// ws[0..65536): W1T bf16, row n=g*64+h (256 x 256B), byte = n*256 + (k*2 ^ ((n&7)<<4))
// ws[65536..73728): W2T bf16, row t=g*16+p (64 x 128B); element slot e (=ks*32+q*8+j)
//   holds W2[g][h(e)][p], h(e) = (e&32)|((e&4)<<2)|((e>>1)&12)|(e&3)  (k-slot permutation
//   matching GEMM1's C^T fragment layout -> GEMM2 needs no hidden transpose), p>=4 zeros.
// ws[73728]: gshift (0=int32 gids, 1=int64) ; ws[73732]: mshift (0=byte mask, 2=int32 mask)
__global__ void prep_kernel(const float* __restrict__ W1, const float* __restrict__ W2,
                            const void* __restrict__ gids_raw, const void* __restrict__ mask_raw,
                            unsigned char* __restrict__ ws){
  int tid = threadIdx.x, bid = blockIdx.x;
  if (bid < 16){
    int chunk = bid*256 + tid;
    int n    = chunk >> 4;
    int kb16 = chunk & 15;
    int d0   = kb16 * 8;
    int g = n >> 6, h = n & 63;
    u16x8 v;
#pragma unroll
    for (int j=0;j<8;++j) v[j] = cvbf(W1[((g*DIM) + d0 + j)*64 + h]);
    unsigned off = (unsigned)n*256 + (((unsigned)kb16*16) ^ (((unsigned)(n&7))<<4));
    *(u16x8*)(ws + off) = v;
  } else {
#pragma unroll
    for (int i=0;i<16;++i){
      int el = tid + i*256;          // 0..4095 elements of W2T
      int t  = el >> 6;              // row t = g*16+p
      int e  = el & 63;              // k-slot within row
      int g = t >> 4, p = t & 15;
      int h = (e & 32) | ((e & 4) << 2) | ((e >> 1) & 12) | (e & 3);
      float f = (p < 4) ? W2[(g*64 + h)*4 + p] : 0.0f;
      unsigned off = 65536u + (unsigned)t*128 + (((unsigned)(e*2)) ^ (((unsigned)(t&7))<<4));
      *(unsigned short*)(ws + off) = cvbf(f);
    }
    if (tid < 64){
      const int* g32 = (const int*)gids_raw;
      int accg = 0;
#pragma unroll
      for (int i=0;i<8;++i) accg |= g32[(tid*8 + i)*2 + 1];
      const unsigned char* m8 = (const unsigned char*)mask_raw;
      int accm = 0;
#pragma unroll
      for (int i=0;i<16;++i){
        int off = tid*16 + i;
        if (off & 3) accm |= m8[off];
      }
      unsigned long long bg = __ballot(accg != 0);
      unsigned long long bm = __ballot(accm != 0);
      if (tid == 0){
        *(int*)(ws + 73728) = (bg == 0ull) ? 1 : 0;
        *(int*)(ws + 73732) = (bm == 0ull) ? 2 : 0;
      }
    }
  }
}

// ---------------- main kernel: persistent, pinned schedule, 32-row units (nt=2) ----------------
#define LDS_W2T 65536
#define LDS_B1  (65536+8192)
#define LDS_TOTAL (65536+8192+1024)

__global__ __launch_bounds__(256, 2)
void actor_kernel(const float* __restrict__ X, const int* __restrict__ gids,
                  const unsigned char* __restrict__ fmask,
                  const float* __restrict__ b1, const float* __restrict__ b2,
                  const unsigned char* __restrict__ ws, float* __restrict__ out){
  __shared__ char smem[LDS_TOTAL];
  const int tid  = threadIdx.x;
  const int wave = tid >> 6, lane = tid & 63;
  const int q    = lane >> 4, rS = lane & 15;
  const int swzA = (rS & 7) << 4;

  const int gshift = *(const int*)(ws + 73728);
  const int mshift = *(const int*)(ws + 73732);

  // --- stage W1T + W2T + b1 to LDS once per block ---
#pragma unroll
  for (int i=0;i<16;++i){
    int off = i*4096 + wave*1024;
    ldsload16(ws + off + lane*16, smem + off);
  }
#pragma unroll
  for (int i=0;i<2;++i){
    int off = i*4096 + wave*1024;
    ldsload16(ws + 65536 + off + lane*16, smem + LDS_W2T + off);
  }
  if (wave == 0)
    ldsload16((const unsigned char*)b1 + lane*16, smem + LDS_B1);
  __syncthreads();   // weights resident

  const long base = (long)blockIdx.x * 512 + wave * 128;
  const f32x4 z = (f32x4){0.f,0.f,0.f,0.f};

#pragma unroll 1
  for (int u=0; u<4; ++u){
    const long row0 = base + u*32 + rS;   // nt=0 row; nt=1 is +16

    // --- loads for both 16-row halves (issued together, TLP hides latency) ---
    int gb0, gb1;
    u32x4 mb0, mb1;
    f32x4 xb[2][4][2];
    {
      gb0 = gids[(size_t)row0 << gshift];
      gb1 = gids[(size_t)(row0 + 16) << gshift];
      if (mshift){
        mb0 = *(const u32x4*)(fmask + row0*16);
        mb1 = *(const u32x4*)(fmask + (row0+16)*16);
      } else {
        unsigned w0 = *(const unsigned*)(fmask + row0*4);
        unsigned w1 = *(const unsigned*)(fmask + (row0+16)*4);
        mb0[0]=w0&0xffu; mb0[1]=(w0>>8)&0xffu; mb0[2]=(w0>>16)&0xffu; mb0[3]=w0>>24;
        mb1[0]=w1&0xffu; mb1[1]=(w1>>8)&0xffu; mb1[2]=(w1>>16)&0xffu; mb1[3]=w1>>24;
      }
      const float* xp0 = X + row0 * DIM + q*8;
      const float* xp1 = X + (row0 + 16) * DIM + q*8;
#pragma unroll
      for (int k=0;k<4;++k){
        xb[0][k][0] = *(const f32x4*)(xp0 + k*32);
        xb[0][k][1] = *(const f32x4*)(xp0 + k*32 + 4);
        xb[1][k][0] = *(const f32x4*)(xp1 + k*32);
        xb[1][k][1] = *(const f32x4*)(xp1 + k*32 + 4);
      }
    }
    __builtin_amdgcn_sched_barrier(0);

    // --- convert to bf16 B-fragments (xb dies here) ---
    s16x8 bfr[2][4];
#pragma unroll
    for (int nt=0;nt<2;++nt)
#pragma unroll
      for (int k=0;k<4;++k){
        s16x8 v;
#pragma unroll
        for (int j=0;j<4;++j){ v[j] = (short)cvbf(xb[nt][k][0][j]); v[j+4] = (short)cvbf(xb[nt][k][1][j]); }
        bfr[nt][k] = v;
      }
    __builtin_amdgcn_sched_barrier(0);

    // --- fused GEMM1 -> +b1/relu -> GEMM2, per mt-pair; each LDS read feeds 2 MFMAs ---
    f32x4 acc2[4][2];
#pragma unroll
    for (int p=0;p<8;++p){
      f32x4 aA0, aA1, aB0, aB1;
#pragma unroll
      for (int k=0;k<4;++k){
        const s16x8 sA = *(const s16x8*)(smem + ((2*p  )*16 + rS)*256 + ((k*64 + q*16) ^ swzA));
        const s16x8 sB = *(const s16x8*)(smem + ((2*p+1)*16 + rS)*256 + ((k*64 + q*16) ^ swzA));
        aA0 = __builtin_amdgcn_mfma_f32_16x16x32_bf16(sA, bfr[0][k], (k==0)? z : aA0, 0,0,0);
        aA1 = __builtin_amdgcn_mfma_f32_16x16x32_bf16(sA, bfr[1][k], (k==0)? z : aA1, 0,0,0);
        aB0 = __builtin_amdgcn_mfma_f32_16x16x32_bf16(sB, bfr[0][k], (k==0)? z : aB0, 0,0,0);
        aB1 = __builtin_amdgcn_mfma_f32_16x16x32_bf16(sB, bfr[1][k], (k==0)? z : aB1, 0,0,0);
      }
      const f32x4 b1A = *(const f32x4*)(smem + LDS_B1 + (2*p  )*64 + q*16);
      const f32x4 b1B = *(const f32x4*)(smem + LDS_B1 + (2*p+1)*64 + q*16);
      const s16x8 af = *(const s16x8*)(smem + LDS_W2T + ((p>>1)*16 + rS)*128
                                       + (((p&1)*64 + q*16) ^ swzA));
      // nt = 0
      {
        f32x4 vA = aA0 + b1A;
        f32x4 vB = aB0 + b1B;
#pragma unroll
        for (int j=0;j<4;++j){
          vA[j] = vA[j] > 0.f ? vA[j] : 0.f;
          vB[j] = vB[j] > 0.f ? vB[j] : 0.f;
        }
        s16x8 hf;
#pragma unroll
        for (int j=0;j<4;++j){ hf[j] = (short)cvbf(vA[j]); hf[j+4] = (short)cvbf(vB[j]); }
        acc2[p>>1][0] = __builtin_amdgcn_mfma_f32_16x16x32_bf16(
            af, hf, (p&1) ? acc2[p>>1][0] : z, 0,0,0);
      }
      // nt = 1
      {
        f32x4 vA = aA1 + b1A;
        f32x4 vB = aB1 + b1B;
#pragma unroll
        for (int j=0;j<4;++j){
          vA[j] = vA[j] > 0.f ? vA[j] : 0.f;
          vB[j] = vB[j] > 0.f ? vB[j] : 0.f;
        }
        s16x8 hf;
#pragma unroll
        for (int j=0;j<4;++j){ hf[j] = (short)cvbf(vA[j]); hf[j+4] = (short)cvbf(vB[j]); }
        acc2[p>>1][1] = __builtin_amdgcn_mfma_f32_16x16x32_bf16(
            af, hf, (p&1) ? acc2[p>>1][1] : z, 0,0,0);
      }
      __builtin_amdgcn_sched_barrier(0);
    }

    // --- epilogue nt=0 ---
    {
      int g = gb0;
      f32x4 lv = acc2[0][0];
      lv = (g==1) ? acc2[1][0] : lv;
      lv = (g==2) ? acc2[2][0] : lv;
      lv = (g==3) ? acc2[3][0] : lv;
      const f32x4 bs = *(const f32x4*)(b2 + g*4);
      f32x4 li;
#pragma unroll
      for (int p=0;p<4;++p)
        li[p] = mb0[p] ? (lv[p] + bs[p]) : -1e9f;
      float m = fmaxf(fmaxf(li[0],li[1]), fmaxf(li[2],li[3]));
      f32x4 e;
#pragma unroll
      for (int p=0;p<4;++p) e[p] = __expf(li[p] - m);
      float inv = 1.0f / (e[0]+e[1]+e[2]+e[3]);
      f32x4 o;
#pragma unroll
      for (int p=0;p<4;++p) o[p] = e[p] * inv;
      if (q == 0)
        *(f32x4*)(out + row0*4) = o;
    }
    // --- epilogue nt=1 ---
    {
      int g = gb1;
      f32x4 lv = acc2[0][1];
      lv = (g==1) ? acc2[1][1] : lv;
      lv = (g==2) ? acc2[2][1] : lv;
      lv = (g==3) ? acc2[3][1] : lv;
      const f32x4 bs = *(const f32x4*)(b2 + g*4);
      f32x4 li;
#pragma unroll
      for (int p=0;p<4;++p)
        li[p] = mb1[p] ? (lv[p] + bs[p]) : -1e9f;
      float m = fmaxf(fmaxf(li[0],li[1]), fmaxf(li[2],li[3]));
      f32x4 e;
#pragma unroll
      for (int p=0;p<4;++p) e[p] = __expf(li[p] - m);
      float inv = 1.0f / (e[0]+e[1]+e[2]+e[3]);
      f32x4 o;
#pragma unroll
      for (int p=0;p<4;++p) o[p] = e[p] * inv;
      if (q == 0)
        *(f32x4*)(out + (row0+16)*4) = o;
    }
  }
}

extern "C" void kernel_launch(void* const* d_in, const int* in_sizes, int n_in,
                              void* d_out, int out_size, void* d_ws, size_t ws_size,
                              hipStream_t stream){
  const float* X  = (const float*)d_in[0];
  const void*  gi = d_in[1];
  const void*  fm = d_in[2];
  const float* W1 = (const float*)d_in[3];
  const float* b1 = (const float*)d_in[4];
  const float* W2 = (const float*)d_in[5];
  const float* b2 = (const float*)d_in[6];
  unsigned char* ws = (unsigned char*)d_ws;
  float* out = (float*)d_out;

  prep_kernel<<<dim3(17), dim3(256), 0, stream>>>(W1, W2, gi, fm, ws);
  actor_kernel<<<dim3(512), dim3(256), 0, stream>>>(X, (const int*)gi,
                                                    (const unsigned char*)fm,
                                                    b1, b2, ws, out);
}